// Round 1
// baseline (174.097 us; speedup 1.0000x reference)
//
#include <hip/hip_runtime.h>

#define Hh 512
#define Ww 512
#define NPIX (Hh*Ww)
#define BATCH 4
#define WINSZ 15
#define HALO 7
#define BINS 64

__device__ __forceinline__ unsigned fkey(float f) {
    unsigned u = __float_as_uint(f);
    return (u & 0x80000000u) ? ~u : (u | 0x80000000u);
}
__device__ __forceinline__ float funkey(unsigned k) {
    unsigned u = (k & 0x80000000u) ? (k & 0x7FFFFFFFu) : ~k;
    return __uint_as_float(u);
}

__global__ void k_init(unsigned* hist, unsigned* mm) {
    int t = threadIdx.x;
    if (t < BATCH*BINS) hist[t] = 0u;
    if (t < BATCH) { mm[2*t] = 0xFFFFFFFFu; mm[2*t+1] = 0u; }
}

__global__ __launch_bounds__(256) void k_hist(const float* __restrict__ in,
                                              unsigned* __restrict__ hist) {
    __shared__ unsigned lh[BINS];
    const int tid = threadIdx.x;
    if (tid < BINS) lh[tid] = 0u;
    __syncthreads();
    const int img = blockIdx.x >> 6;
    const int chunk = blockIdx.x & 63;
    const float* Lp = in + (size_t)img * 3 * NPIX;
    const int base = chunk * 4096;
    #pragma unroll
    for (int t = 0; t < 16; ++t) {
        float lv = Lp[base + t*256 + tid];
        float ln = fminf(fmaxf(lv / 100.0f, 0.0f), 1.0f);
        int idx = (int)(ln * 64.0f); idx = min(idx, 63);
        atomicAdd(&lh[idx], 1u);
    }
    __syncthreads();
    if (tid < BINS) atomicAdd(&hist[img*BINS + tid], lh[tid]);
}

__global__ __launch_bounds__(256) void k_main(const float* __restrict__ in,
        const unsigned* __restrict__ hist, unsigned* __restrict__ mm,
        float* __restrict__ Sbuf, float* __restrict__ out) {
    __shared__ int   s_idx[30][33];
    __shared__ float s_ln[30][33];
    __shared__ float s_a[30][33];
    __shared__ float s_b[30][33];
    __shared__ float s_ca[16][33];
    __shared__ float s_cb[16][33];
    __shared__ float red[8];

    const int tx = threadIdx.x, ty = threadIdx.y;
    const int tid = ty*16 + tx;
    const int bx = blockIdx.x * 16, by = blockIdx.y * 16;
    const int img = blockIdx.z;
    const float* Lp = in + (size_t)img * 3 * NPIX;
    const float* Ap = Lp + NPIX;
    const float* Bp = Lp + 2*NPIX;

    // Stage tile + halo. OOB: idx=-1 (never matches), a/b = 0 (zero padding).
    for (int l = tid; l < 900; l += 256) {
        int r = l / 30, c = l - r*30;
        int gy = by - HALO + r, gx = bx - HALO + c;
        int iv = -1; float lnv = 0.f, av = 0.f, bv = 0.f;
        if (gy >= 0 && gy < Hh && gx >= 0 && gx < Ww) {
            int g = gy*Ww + gx;
            float lv = Lp[g];
            lnv = fminf(fmaxf(lv / 100.0f, 0.0f), 1.0f);
            iv = min((int)(lnv * 64.0f), 63);
            av = (Ap[g] + 128.0f) / 255.0f;
            bv = (Bp[g] + 128.0f) / 255.0f;
        }
        s_idx[r][c] = iv; s_ln[r][c] = lnv; s_a[r][c] = av; s_b[r][c] = bv;
    }
    __syncthreads();

    // Separable stage 1: vertical 15-sums of a,b for each (output row, staged col)
    for (int l = tid; l < 480; l += 256) {
        int r = l / 30, c = l - r*30;
        float sa = 0.f, sb = 0.f;
        #pragma unroll
        for (int dy = 0; dy < WINSZ; ++dy) { sa += s_a[r+dy][c]; sb += s_b[r+dy][c]; }
        s_ca[r][c] = sa; s_cb[r][c] = sb;
    }
    __syncthreads();

    // Own-bin window count (brute force over 15x15)
    const int cbin = s_idx[ty+HALO][tx+HALO];
    int cnt = 0;
    #pragma unroll 1
    for (int dy = 0; dy < WINSZ; ++dy) {
        #pragma unroll
        for (int dx = 0; dx < WINSZ; ++dx)
            cnt += (s_idx[ty+dy][tx+dx] == cbin) ? 1 : 0;
    }
    float suma = 0.f, sumb = 0.f;
    #pragma unroll
    for (int dx = 0; dx < WINSZ; ++dx) { suma += s_ca[ty][tx+dx]; sumb += s_cb[ty][tx+dx]; }

    const int gy = by + ty, gx = bx + tx;
    const int rows = min(gy+HALO, Hh-1) - max(gy-HALO, 0) + 1;
    const int cols = min(gx+HALO, Ww-1) - max(gx-HALO, 0) + 1;
    const float nf = (float)(rows*cols);

    float p_loc  = (float)cnt / nf;
    float p_glob = (float)hist[img*BINS + cbin] * (1.0f/(float)NPIX);
    float arg = 0.9f*p_loc + 0.1f*p_glob + 1e-6f;
    float S = -logf(arg);
    Sbuf[img*NPIX + gy*Ww + gx] = S;

    float mu_a = suma / nf, mu_b = sumb / nf;
    float Lnc = s_ln[ty+HALO][tx+HALO];
    float anc = s_a[ty+HALO][tx+HALO];
    float bnc = s_b[ty+HALO][tx+HALO];
    float Lperp = Lnc - 0.5f*(anc - mu_a) - 0.5f*(bnc - mu_b);
    Lperp = fminf(fmaxf(Lperp, 0.0f), 1.0f);
    out[img*NPIX + gy*Ww + gx] = Lperp;

    // Block min/max of S -> one atomic pair per block
    float smin = S, smax = S;
    #pragma unroll
    for (int off = 32; off >= 1; off >>= 1) {
        smin = fminf(smin, __shfl_xor(smin, off));
        smax = fmaxf(smax, __shfl_xor(smax, off));
    }
    const int wid = tid >> 6;
    if ((tid & 63) == 0) { red[wid] = smin; red[4+wid] = smax; }
    __syncthreads();
    if (tid == 0) {
        float m0 = fminf(fminf(red[0],red[1]), fminf(red[2],red[3]));
        float m1 = fmaxf(fmaxf(red[4],red[5]), fmaxf(red[6],red[7]));
        atomicMin(&mm[2*img],   fkey(m0));
        atomicMax(&mm[2*img+1], fkey(m1));
    }
}

__global__ __launch_bounds__(256) void k_norm(const float* __restrict__ Sbuf,
        const unsigned* __restrict__ mm, float* __restrict__ out) {
    const int i = blockIdx.x*256 + threadIdx.x;
    const int img = i >> 18;   // NPIX = 2^18
    float smin = funkey(mm[2*img]);
    float smax = funkey(mm[2*img+1]);
    float S = Sbuf[i];
    out[i] = (S - smin) / (smax - smin + 1e-6f);
}

extern "C" void kernel_launch(void* const* d_in, const int* in_sizes, int n_in,
                              void* d_out, int out_size, void* d_ws, size_t ws_size,
                              hipStream_t stream) {
    const float* in = (const float*)d_in[0];
    float* out = (float*)d_out;
    unsigned* hist = (unsigned*)d_ws;
    unsigned* mm   = hist + BATCH*BINS;
    float* Sbuf = (float*)((char*)d_ws + 4096);

    k_init<<<1, 256, 0, stream>>>(hist, mm);
    k_hist<<<BATCH*64, 256, 0, stream>>>(in, hist);
    dim3 grid(Ww/16, Hh/16, BATCH), blk(16, 16);
    k_main<<<grid, blk, 0, stream>>>(in, hist, mm, Sbuf, out);
    k_norm<<<(BATCH*NPIX)/256, 256, 0, stream>>>(Sbuf, mm, out + (size_t)BATCH*NPIX);
}

// Round 2
// 130.137 us; speedup vs baseline: 1.3378x; 1.3378x over previous
//
#include <hip/hip_runtime.h>

#define Hh 512
#define Ww 512
#define NPIX (Hh*Ww)
#define BATCH 4

__device__ __forceinline__ unsigned fkey(float f) {
    unsigned u = __float_as_uint(f);
    return (u & 0x80000000u) ? ~u : (u | 0x80000000u);
}
__device__ __forceinline__ float funkey(unsigned k) {
    unsigned u = (k & 0x80000000u) ? (k & 0x7FFFFFFFu) : ~k;
    return __uint_as_float(u);
}

__global__ __launch_bounds__(256) void k_hist(const float* __restrict__ in,
                                              unsigned* __restrict__ hist) {
    __shared__ unsigned lh[64];
    const int tid = threadIdx.x;
    if (tid < 64) lh[tid] = 0u;
    __syncthreads();
    const int img = blockIdx.x >> 6, chunk = blockIdx.x & 63;
    const float4* Lp = (const float4*)(in + (size_t)img * 3 * NPIX) + chunk * 1024;
    #pragma unroll
    for (int t = 0; t < 4; ++t) {
        float4 v = Lp[t*256 + tid];
        float f[4] = {v.x, v.y, v.z, v.w};
        #pragma unroll
        for (int j = 0; j < 4; ++j) {
            float ln = fminf(fmaxf(f[j] / 100.0f, 0.0f), 1.0f);
            int idx = min((int)(ln * 64.0f), 63);
            atomicAdd(&lh[idx], 1u);
        }
    }
    __syncthreads();
    if (tid < 64) atomicAdd(&hist[img*64 + tid], lh[tid]);
}

// Tile: 16 wide x 32 tall outputs per block; 16x16 threads, 2 output rows/thread.
// Staged halo region: 30 cols x 46 rows.
__global__ __launch_bounds__(256) void k_main(const float* __restrict__ in,
        const unsigned* __restrict__ hist, unsigned* __restrict__ mmin,
        unsigned* __restrict__ mmax, float* __restrict__ Sbuf, float* __restrict__ out) {
    __shared__ __align__(16) unsigned s_pk[46][12]; // packed bin bytes, 48B row stride (30 used)
    __shared__ float s_c[46][35];                   // an+bn combined chroma
    __shared__ float s_cc[32][33];                  // vertical 15-sums at output rows
    __shared__ float s_lnc[32][17];                 // center Ln
    __shared__ float red[8];

    const int tx = threadIdx.x, ty = threadIdx.y;
    const int tid = ty*16 + tx;
    const int bx = blockIdx.x * 16, by = blockIdx.y * 32;
    const int img = blockIdx.z;
    const float* Lp = in + (size_t)img * 3 * NPIX;
    const float* Ap = Lp + NPIX;
    const float* Bp = Lp + 2*NPIX;
    char* sp = (char*)s_pk;

    // ---- stage: 46x30 pixels ----
    for (int l = tid; l < 1380; l += 256) {
        int r = l / 30, c = l - r*30;
        int gy = by - 7 + r, gx = bx - 7 + c;
        unsigned char bb = 0x7F; float cv = 0.f, lnv = 0.f;
        if (gy >= 0 && gy < Hh && gx >= 0 && gx < Ww) {
            int g = gy*Ww + gx;
            lnv = fminf(fmaxf(Lp[g] / 100.0f, 0.0f), 1.0f);
            bb = (unsigned char)min((int)(lnv * 64.0f), 63);
            cv = (Ap[g] + 128.0f)/255.0f + (Bp[g] + 128.0f)/255.0f;
        }
        sp[r*48 + c] = bb;
        s_c[r][c] = cv;
        int rr = r - 7, cc = c - 7;
        if (rr >= 0 && rr < 32 && cc >= 0 && cc < 16) s_lnc[rr][cc] = lnv;
    }
    if (tid < 46) *(unsigned short*)(sp + tid*48 + 30) = 0x0000;
    __syncthreads();

    // ---- vertical 15-sums of combined chroma, paired output rows ----
    for (int l = tid; l < 512; l += 256) {
        int q = l >> 5, c = l & 31;
        if (c < 30) {
            float mid = 0.f;
            #pragma unroll
            for (int k = 1; k < 15; ++k) mid += s_c[2*q + k][c];
            s_cc[2*q][c]   = mid + s_c[2*q][c];
            s_cc[2*q+1][c] = mid + s_c[2*q+15][c];
        }
    }
    __syncthreads();

    // ---- per-thread window byte masks (bytes [tx, tx+14], high bit per byte) ----
    unsigned wm[8];
    #pragma unroll
    for (int i = 0; i < 8; ++i) {
        unsigned m = 0;
        #pragma unroll
        for (int j = 0; j < 4; ++j) {
            int bi = 4*i + j;
            if (bi >= tx && bi < tx + 15) m |= 0x80u << (8*j);
        }
        wm[i] = m;
    }

    const int r0 = 2*ty;
    const unsigned cb0 = (unsigned char)sp[(r0+7)*48 + tx+7];
    const unsigned cb1 = (unsigned char)sp[(r0+8)*48 + tx+7];
    const unsigned cb40 = cb0 * 0x01010101u;
    const unsigned cb41 = cb1 * 0x01010101u;
    const unsigned K = 0x7F7F7F7Fu;
    int c0 = 0, c1 = 0;

    { // staged row r0: center0 only
        const uint4* rp = (const uint4*)(sp + r0*48);
        uint4 lo = rp[0], hi = rp[1];
        unsigned d[8] = {lo.x,lo.y,lo.z,lo.w,hi.x,hi.y,hi.z,hi.w};
        #pragma unroll
        for (int i = 0; i < 8; ++i) c0 += __popc(~((d[i]^cb40)+K) & wm[i]);
    }
    #pragma unroll 2
    for (int k = 1; k < 15; ++k) { // both centers
        const uint4* rp = (const uint4*)(sp + (r0+k)*48);
        uint4 lo = rp[0], hi = rp[1];
        unsigned d[8] = {lo.x,lo.y,lo.z,lo.w,hi.x,hi.y,hi.z,hi.w};
        #pragma unroll
        for (int i = 0; i < 8; ++i) {
            c0 += __popc(~((d[i]^cb40)+K) & wm[i]);
            c1 += __popc(~((d[i]^cb41)+K) & wm[i]);
        }
    }
    { // staged row r0+15: center1 only
        const uint4* rp = (const uint4*)(sp + (r0+15)*48);
        uint4 lo = rp[0], hi = rp[1];
        unsigned d[8] = {lo.x,lo.y,lo.z,lo.w,hi.x,hi.y,hi.z,hi.w};
        #pragma unroll
        for (int i = 0; i < 8; ++i) c1 += __popc(~((d[i]^cb41)+K) & wm[i]);
    }

    // ---- horizontal chroma sums ----
    float sc0 = 0.f, sc1 = 0.f;
    #pragma unroll
    for (int dx = 0; dx < 15; ++dx) {
        sc0 += s_cc[r0][tx+dx];
        sc1 += s_cc[r0+1][tx+dx];
    }

    // ---- finish both output pixels ----
    const int gx = bx + tx;
    const int gy0 = by + r0, gy1 = gy0 + 1;
    const int cols  = min(gx+7, Ww-1) - max(gx-7, 0) + 1;
    const int rows0 = min(gy0+7, Hh-1) - max(gy0-7, 0) + 1;
    const int rows1 = min(gy1+7, Hh-1) - max(gy1-7, 0) + 1;
    const float nf0 = (float)(rows0*cols), nf1 = (float)(rows1*cols);

    const float pg0 = (float)hist[img*64 + cb0] * (1.0f/(float)NPIX);
    const float pg1 = (float)hist[img*64 + cb1] * (1.0f/(float)NPIX);
    const float S0 = -logf(0.9f*((float)c0/nf0) + 0.1f*pg0 + 1e-6f);
    const float S1 = -logf(0.9f*((float)c1/nf1) + 0.1f*pg1 + 1e-6f);
    Sbuf[img*NPIX + gy0*Ww + gx] = S0;
    Sbuf[img*NPIX + gy1*Ww + gx] = S1;

    float lp0 = s_lnc[r0][tx]   - 0.5f*(s_c[r0+7][tx+7] - sc0/nf0);
    float lp1 = s_lnc[r0+1][tx] - 0.5f*(s_c[r0+8][tx+7] - sc1/nf1);
    out[img*NPIX + gy0*Ww + gx] = fminf(fmaxf(lp0, 0.0f), 1.0f);
    out[img*NPIX + gy1*Ww + gx] = fminf(fmaxf(lp1, 0.0f), 1.0f);

    // ---- block min/max of S ----
    float smin = fminf(S0, S1), smax = fmaxf(S0, S1);
    #pragma unroll
    for (int off = 32; off >= 1; off >>= 1) {
        smin = fminf(smin, __shfl_xor(smin, off));
        smax = fmaxf(smax, __shfl_xor(smax, off));
    }
    const int wid = tid >> 6;
    if ((tid & 63) == 0) { red[wid] = smin; red[4+wid] = smax; }
    __syncthreads();
    if (tid == 0) {
        float m0 = fminf(fminf(red[0],red[1]), fminf(red[2],red[3]));
        float m1 = fmaxf(fmaxf(red[4],red[5]), fmaxf(red[6],red[7]));
        atomicMin(&mmin[img], fkey(m0));
        atomicMax(&mmax[img], fkey(m1));
    }
}

__global__ __launch_bounds__(256) void k_norm4(const float4* __restrict__ Sbuf,
        const unsigned* __restrict__ mmin, const unsigned* __restrict__ mmax,
        float4* __restrict__ out) {
    const int i = blockIdx.x*256 + threadIdx.x;
    const int img = i >> 16;                       // 65536 float4 per image
    const float smin = funkey(mmin[img]);
    const float smax = funkey(mmax[img]);
    const float inv = 1.0f / (smax - smin + 1e-6f);
    float4 S = Sbuf[i];
    float4 r;
    r.x = (S.x - smin) * inv; r.y = (S.y - smin) * inv;
    r.z = (S.z - smin) * inv; r.w = (S.w - smin) * inv;
    out[i] = r;
}

extern "C" void kernel_launch(void* const* d_in, const int* in_sizes, int n_in,
                              void* d_out, int out_size, void* d_ws, size_t ws_size,
                              hipStream_t stream) {
    const float* in = (const float*)d_in[0];
    float* out = (float*)d_out;
    unsigned* hist = (unsigned*)d_ws;                 // 4*64*4 = 1024 B
    unsigned* mmax = hist + 256;                      // 16 B @ 1024
    unsigned* mmin = hist + 260;                      // 16 B @ 1040
    float* Sbuf = (float*)((char*)d_ws + 4096);

    hipMemsetAsync(d_ws, 0, 1040, stream);                  // hist + mmax keys = 0
    hipMemsetAsync((char*)d_ws + 1040, 0xFF, 16, stream);   // mmin keys = UINT_MAX

    k_hist<<<BATCH*64, 256, 0, stream>>>(in, hist);
    dim3 grid(Ww/16, Hh/32, BATCH), blk(16, 16);
    k_main<<<grid, blk, 0, stream>>>(in, hist, mmin, mmax, Sbuf, out);
    k_norm4<<<(BATCH*NPIX/4)/256, 256, 0, stream>>>((const float4*)Sbuf, mmin, mmax,
                                                    (float4*)(out + (size_t)BATCH*NPIX));
}

// Round 3
// 124.661 us; speedup vs baseline: 1.3966x; 1.0439x over previous
//
#include <hip/hip_runtime.h>

#define Hh 512
#define Ww 512
#define NPIX (Hh*Ww)
#define BATCH 4

__device__ __forceinline__ unsigned fkey(float f) {
    unsigned u = __float_as_uint(f);
    return (u & 0x80000000u) ? ~u : (u | 0x80000000u);
}
__device__ __forceinline__ float funkey(unsigned k) {
    unsigned u = (k & 0x80000000u) ? (k & 0x7FFFFFFFu) : ~k;
    return __uint_as_float(u);
}

__global__ __launch_bounds__(256) void k_hist(const float* __restrict__ in,
                                              unsigned* __restrict__ hist) {
    __shared__ unsigned lh[64];
    const int tid = threadIdx.x;
    if (tid < 64) lh[tid] = 0u;
    __syncthreads();
    const int img = blockIdx.x >> 7, chunk = blockIdx.x & 127;
    const float4* Lp = (const float4*)(in + (size_t)img * 3 * NPIX) + chunk * 512;
    #pragma unroll
    for (int t = 0; t < 2; ++t) {
        float4 v = Lp[t*256 + tid];
        float f[4] = {v.x, v.y, v.z, v.w};
        #pragma unroll
        for (int j = 0; j < 4; ++j) {
            float ln = fminf(fmaxf(f[j] / 100.0f, 0.0f), 1.0f);
            int idx = min((int)(ln * 64.0f), 63);
            atomicAdd(&lh[idx], 1u);
        }
    }
    __syncthreads();
    if (tid < 64) atomicAdd(&hist[img*64 + tid], lh[tid]);
}

// Tile 16 wide x 32 tall; block 16x16; 2 output rows/thread.
// Staged: 46 rows x 32 cols starting at (by-7, bx-8). Packed-bin row stride 48B
// (dwords 0..7 = bins, 8..11 = zero pad). Window for center tx = staged bytes
// [tx+1, tx+15], spanning dwords j0..j0+4 where j0 = (tx+1)>>2.
__global__ __launch_bounds__(256) void k_main(const float* __restrict__ in,
        const unsigned* __restrict__ hist, unsigned* __restrict__ mmin,
        unsigned* __restrict__ mmax, float* __restrict__ Sbuf, float* __restrict__ out)
{
    __shared__ unsigned s_pk[46*12];
    __shared__ float s_c[46*36];
    __shared__ float s_cc[32*33];
    __shared__ float s_lnc[32*16];
    __shared__ float red[8];

    const int tx = threadIdx.x, ty = threadIdx.y;
    const int tid = ty*16 + tx;
    const int bx = blockIdx.x * 16, by = blockIdx.y * 32;
    const int img = blockIdx.z;
    const float* Lp = in + (size_t)img * 3 * NPIX;

    // ---- per-thread window byte masks (5 dwords, high bit per window byte) ----
    const int s = tx + 1;
    const int j0 = s >> 2;
    const unsigned m20 = 0x7FFFu << (s & 3);
    unsigned wm[5];
    #pragma unroll
    for (int i = 0; i < 5; ++i) {
        unsigned n = (m20 >> (4*i)) & 0xFu;
        wm[i] = (n&1u)*0x80u | (n&2u)*0x4000u | (n&4u)*0x200000u | (n&8u)*0x10000000u;
    }

    // ---- stage 46x32 (quad-granular bounds: quads fully in or out) ----
    for (int l = tid; l < 368; l += 256) {
        const int r = l >> 3, c4 = l & 7;
        const int gy = by - 7 + r;
        const int gx0 = bx - 8 + c4*4;
        unsigned pk = 0x7F7F7F7Fu;
        float4 cv = {0.f, 0.f, 0.f, 0.f};
        if (gy >= 0 && gy < Hh && gx0 >= 0 && gx0 < Ww) {
            const int g = gy*Ww + gx0;
            const float4 Lv = *(const float4*)(Lp + g);
            const float4 Av = *(const float4*)(Lp + NPIX + g);
            const float4 Bv = *(const float4*)(Lp + 2*NPIX + g);
            const float l0 = fminf(fmaxf(Lv.x / 100.0f, 0.0f), 1.0f);
            const float l1 = fminf(fmaxf(Lv.y / 100.0f, 0.0f), 1.0f);
            const float l2 = fminf(fmaxf(Lv.z / 100.0f, 0.0f), 1.0f);
            const float l3 = fminf(fmaxf(Lv.w / 100.0f, 0.0f), 1.0f);
            const int b0 = min((int)(l0*64.0f), 63), b1 = min((int)(l1*64.0f), 63);
            const int b2 = min((int)(l2*64.0f), 63), b3 = min((int)(l3*64.0f), 63);
            pk = (unsigned)b0 | ((unsigned)b1<<8) | ((unsigned)b2<<16) | ((unsigned)b3<<24);
            const float k255 = 1.0f/255.0f;
            cv.x = (Av.x+128.0f)*k255 + (Bv.x+128.0f)*k255;
            cv.y = (Av.y+128.0f)*k255 + (Bv.y+128.0f)*k255;
            cv.z = (Av.z+128.0f)*k255 + (Bv.z+128.0f)*k255;
            cv.w = (Av.w+128.0f)*k255 + (Bv.w+128.0f)*k255;
            if (r >= 7 && r < 39 && c4 >= 2 && c4 <= 5) {
                float4 lv4 = {l0, l1, l2, l3};
                *(float4*)&s_lnc[(r-7)*16 + 4*(c4-2)] = lv4;
            }
        }
        s_pk[r*12 + c4] = pk;
        *(float4*)&s_c[r*36 + c4*4] = cv;
    }
    for (int l = tid; l < 184; l += 256) s_pk[(l>>2)*12 + 8 + (l&3)] = 0u;
    __syncthreads();

    // ---- vertical chroma 15-sums, paired output rows ----
    for (int l = tid; l < 512; l += 256) {
        const int q = l >> 5, c = l & 31;
        float mid = 0.f;
        #pragma unroll
        for (int k = 1; k < 15; ++k) mid += s_c[(2*q+k)*36 + c];
        s_cc[(2*q)*33 + c]   = mid + s_c[(2*q)*36 + c];
        s_cc[(2*q+1)*33 + c] = mid + s_c[(2*q+15)*36 + c];
    }
    __syncthreads();

    // ---- own-bin match count: 5 dwords/row, 2 centers ----
    const int r0 = 2*ty;
    const int cbyte = tx + 8;
    const unsigned cb0 = (s_pk[(r0+7)*12 + (cbyte>>2)] >> (8*(cbyte&3))) & 0xFFu;
    const unsigned cb1 = (s_pk[(r0+8)*12 + (cbyte>>2)] >> (8*(cbyte&3))) & 0xFFu;
    const unsigned cb40 = cb0 * 0x01010101u;
    const unsigned cb41 = cb1 * 0x01010101u;
    const unsigned K = 0x7F7F7F7Fu;
    int c0 = 0, c1 = 0;
    const unsigned* rp = s_pk + r0*12 + j0;

    { // k = 0: center0 only
        unsigned d0=rp[0], d1=rp[1], d2=rp[2], d3=rp[3], d4=rp[4];
        c0 += __popc(~((d0^cb40)+K) & wm[0]);
        c0 += __popc(~((d1^cb40)+K) & wm[1]);
        c0 += __popc(~((d2^cb40)+K) & wm[2]);
        c0 += __popc(~((d3^cb40)+K) & wm[3]);
        c0 += __popc(~((d4^cb40)+K) & wm[4]);
    }
    #pragma unroll 2
    for (int k = 1; k < 15; ++k) { // both centers
        const unsigned* rk = rp + k*12;
        unsigned d0=rk[0], d1=rk[1], d2=rk[2], d3=rk[3], d4=rk[4];
        c0 += __popc(~((d0^cb40)+K) & wm[0]);
        c1 += __popc(~((d0^cb41)+K) & wm[0]);
        c0 += __popc(~((d1^cb40)+K) & wm[1]);
        c1 += __popc(~((d1^cb41)+K) & wm[1]);
        c0 += __popc(~((d2^cb40)+K) & wm[2]);
        c1 += __popc(~((d2^cb41)+K) & wm[2]);
        c0 += __popc(~((d3^cb40)+K) & wm[3]);
        c1 += __popc(~((d3^cb41)+K) & wm[3]);
        c0 += __popc(~((d4^cb40)+K) & wm[4]);
        c1 += __popc(~((d4^cb41)+K) & wm[4]);
    }
    { // k = 15: center1 only
        const unsigned* rk = rp + 180;
        unsigned d0=rk[0], d1=rk[1], d2=rk[2], d3=rk[3], d4=rk[4];
        c1 += __popc(~((d0^cb41)+K) & wm[0]);
        c1 += __popc(~((d1^cb41)+K) & wm[1]);
        c1 += __popc(~((d2^cb41)+K) & wm[2]);
        c1 += __popc(~((d3^cb41)+K) & wm[3]);
        c1 += __popc(~((d4^cb41)+K) & wm[4]);
    }

    // ---- horizontal chroma sums ----
    float sc0 = 0.f, sc1 = 0.f;
    const float* ccp = s_cc + r0*33 + s;
    #pragma unroll
    for (int dx = 0; dx < 15; ++dx) { sc0 += ccp[dx]; sc1 += ccp[33+dx]; }

    // ---- epilogue: S, L_perp, block min/max ----
    const int gx = bx + tx;
    const int gy0 = by + r0;
    const int cols  = min(gx+7, Ww-1) - max(gx-7, 0) + 1;
    const int rows0 = min(gy0+7, Hh-1) - max(gy0-7, 0) + 1;
    const int rows1 = min(gy0+8, Hh-1) - max(gy0-6, 0) + 1;
    const float inv0 = __builtin_amdgcn_rcpf((float)(rows0*cols));
    const float inv1 = __builtin_amdgcn_rcpf((float)(rows1*cols));
    const float pg0 = (float)hist[img*64 + cb0] * (1.0f/262144.0f);
    const float pg1 = (float)hist[img*64 + cb1] * (1.0f/262144.0f);
    const float S0 = -__logf(0.9f*((float)c0*inv0) + 0.1f*pg0 + 1e-6f);
    const float S1 = -__logf(0.9f*((float)c1*inv1) + 0.1f*pg1 + 1e-6f);
    const int gbase = img*NPIX + gy0*Ww + gx;
    Sbuf[gbase]      = S0;
    Sbuf[gbase + Ww] = S1;

    const float lp0 = s_lnc[r0*16 + tx]     - 0.5f*(s_c[(r0+7)*36 + tx+8] - sc0*inv0);
    const float lp1 = s_lnc[(r0+1)*16 + tx] - 0.5f*(s_c[(r0+8)*36 + tx+8] - sc1*inv1);
    out[gbase]      = fminf(fmaxf(lp0, 0.f), 1.f);
    out[gbase + Ww] = fminf(fmaxf(lp1, 0.f), 1.f);

    float smin = fminf(S0, S1), smax = fmaxf(S0, S1);
    #pragma unroll
    for (int off = 32; off >= 1; off >>= 1) {
        smin = fminf(smin, __shfl_xor(smin, off));
        smax = fmaxf(smax, __shfl_xor(smax, off));
    }
    const int wid = tid >> 6;
    if ((tid & 63) == 0) { red[wid] = smin; red[4+wid] = smax; }
    __syncthreads();
    if (tid == 0) {
        float m0 = fminf(fminf(red[0],red[1]), fminf(red[2],red[3]));
        float m1 = fmaxf(fmaxf(red[4],red[5]), fmaxf(red[6],red[7]));
        atomicMin(&mmin[img], fkey(m0));
        atomicMax(&mmax[img], fkey(m1));
    }
}

__global__ __launch_bounds__(256) void k_norm4(const float4* __restrict__ Sbuf,
        const unsigned* __restrict__ mmin, const unsigned* __restrict__ mmax,
        float4* __restrict__ out) {
    const int i = blockIdx.x*256 + threadIdx.x;
    const int img = i >> 16;                       // 65536 float4 per image
    const float smin = funkey(mmin[img]);
    const float smax = funkey(mmax[img]);
    const float inv = 1.0f / (smax - smin + 1e-6f);
    float4 S = Sbuf[i];
    float4 r;
    r.x = (S.x - smin) * inv; r.y = (S.y - smin) * inv;
    r.z = (S.z - smin) * inv; r.w = (S.w - smin) * inv;
    out[i] = r;
}

extern "C" void kernel_launch(void* const* d_in, const int* in_sizes, int n_in,
                              void* d_out, int out_size, void* d_ws, size_t ws_size,
                              hipStream_t stream) {
    const float* in = (const float*)d_in[0];
    float* out = (float*)d_out;
    unsigned* hist = (unsigned*)d_ws;                 // 1024 B
    unsigned* mmax = hist + 256;                      // 16 B @ 1024
    unsigned* mmin = hist + 260;                      // 16 B @ 1040
    float* Sbuf = (float*)((char*)d_ws + 4096);

    hipMemsetAsync(d_ws, 0, 1040, stream);                  // hist + mmax keys = 0
    hipMemsetAsync((char*)d_ws + 1040, 0xFF, 16, stream);   // mmin keys = UINT_MAX

    k_hist<<<BATCH*128, 256, 0, stream>>>(in, hist);
    dim3 grid(Ww/16, Hh/32, BATCH), blk(16, 16);
    k_main<<<grid, blk, 0, stream>>>(in, hist, mmin, mmax, Sbuf, out);
    k_norm4<<<(BATCH*NPIX/4)/256, 256, 0, stream>>>((const float4*)Sbuf, mmin, mmax,
                                                    (float4*)(out + (size_t)BATCH*NPIX));
}